// Round 15
// baseline (111.375 us; speedup 1.0000x reference)
//
#include <hip/hip_runtime.h>
#include <math.h>

#define Nn 512
#define Tt 8
#define Ee 16384
#define NNc (Nn*Nn)          // 262144
#define TNr (Tt*Nn)          // 4096
#define TE  (Tt*Ee)          // 131072
#define CAP 128              // bucket capacity per (t,dst); Poisson(32) => overflow ~1e-35

typedef __bf16 bf16x8 __attribute__((ext_vector_type(8)));
typedef float  f32x4  __attribute__((ext_vector_type(4)));
union BU { uint4 q; bf16x8 v; };

// RNE fp32 -> bf16 hi/lo split, packing two elements into one u32 each.
__device__ __forceinline__ void dec2(float x0, float x1, unsigned &hi, unsigned &lo){
    unsigned u0 = __float_as_uint(x0), u1 = __float_as_uint(x1);
    unsigned t0 = u0 + 0x7FFFu + ((u0>>16)&1u);
    unsigned t1 = u1 + 0x7FFFu + ((u1>>16)&1u);
    hi = (t0>>16) | (t1 & 0xFFFF0000u);
    float h0 = __uint_as_float(t0 & 0xFFFF0000u);
    float h1 = __uint_as_float(t1 & 0xFFFF0000u);
    float l0 = x0 - h0, l1 = x1 - h1;
    unsigned v0 = __float_as_uint(l0), v1 = __float_as_uint(l1);
    unsigned s0 = v0 + 0x7FFFu + ((v0>>16)&1u);
    unsigned s1 = v1 + 0x7FFFu + ((v1>>16)&1u);
    lo = (s0>>16) | (s1 & 0xFFFF0000u);
}

// ---------------- merged prep (blocks 0..63) + fp1 (blocks 64..319)
// fp1: WAVE-PRIVATE 4 rows, no barriers; weights streamed from global (L1/L2),
// LDS used only for 4x-reduced wave-uniform broadcast of activations.
__global__ __launch_bounds__(256) void k_pf(
    const int* __restrict__ ei, const float* __restrict__ W3,
    unsigned short* __restrict__ w3h, unsigned short* __restrict__ w3l,
    int* __restrict__ cnt, int* __restrict__ tag, float4* __restrict__ out4,
    const float* __restrict__ feats, const float* __restrict__ noise,
    const float* __restrict__ Wp1, const float* __restrict__ bp1,
    const float* __restrict__ Wp2, const float* __restrict__ bp2,
    const float* __restrict__ W1, const float* __restrict__ b1,
    float* __restrict__ hh)
{
    __shared__ float sfeat[16][128];
    __shared__ float sh1[16][256];
    __shared__ float semb[16][80];
    int tid = threadIdx.x;
    if (blockIdx.x < 64){
        // ---- prep: targeted zero + W3 bf16 hi/lo split in MFMA-fragment order
        int e = blockIdx.x*256 + tid;   // < 16384
        int a = ei[7*2*Ee + e], b = ei[7*2*Ee + Ee + e];
        int cell = a*Nn + b;
#pragma unroll
        for (int t=0;t<8;++t) tag[t*NNc + cell] = 0;
        if (e < TNr) cnt[e] = 0;
        float4 z = {0.f,0.f,0.f,0.f};
#pragma unroll
        for (int q=0;q<4;++q) out4[q*16384 + e] = z;
        int i    = e & 7;
        int lane = (e>>3) & 63;
        int jt   = (e>>9) & 7;
        int kt   = e>>12;
        int k = kt*32 + (lane>>4)*8 + i;
        int j = jt*16 + (lane&15);
        float x = W3[k*128 + j];
        unsigned u = __float_as_uint(x);
        unsigned t = u + 0x7FFFu + ((u>>16)&1u);
        w3h[e] = (unsigned short)(t>>16);
        float hf = __uint_as_float(t & 0xFFFF0000u);
        float lf = x - hf;
        unsigned v = __float_as_uint(lf);
        unsigned s = v + 0x7FFFu + ((v>>16)&1u);
        w3l[e] = (unsigned short)(s>>16);
        return;
    }
    // ---- fp1: wave w handles global rows r0..r0+3, fully independent
    int w = tid >> 6, lane = tid & 63;
    int lr = w*4;                               // local row base
    int r0 = (blockIdx.x - 64)*16 + lr;         // global row base
    // stage 4 rows of feats (512 floats, 2 float4/lane)
    {
        const float4* __restrict__ src = (const float4*)&feats[(size_t)r0*128];
        float4 v0 = src[lane], v1 = src[64+lane];
        ((float4*)&sfeat[lr][0])[lane]    = v0;
        ((float4*)&sfeat[lr][0])[64+lane] = v1;
    }
    // noise -> semb[:,64:80] (64 floats, 1/lane)
    {
        int r = lane >> 4, k = lane & 15;
        semb[lr+r][64+k] = noise[(size_t)(r0+r)*16 + k];
    }
    __builtin_amdgcn_wave_barrier();
    // phase 1: sh1[r][j] = relu(sfeat@Wp1 + bp1), j = lane*4..+3
    {
        int jb = lane*4;
        float acc[4][4];
#pragma unroll
        for (int r=0;r<4;++r)
#pragma unroll
            for (int q=0;q<4;++q) acc[r][q]=0.f;
        for (int i=0;i<128;i+=4){
            float4 w0 = *(const float4*)&Wp1[(i+0)*256 + jb];
            float4 w1 = *(const float4*)&Wp1[(i+1)*256 + jb];
            float4 w2 = *(const float4*)&Wp1[(i+2)*256 + jb];
            float4 w3 = *(const float4*)&Wp1[(i+3)*256 + jb];
#pragma unroll
            for (int r=0;r<4;++r){
                float4 f = *(const float4*)&sfeat[lr+r][i];
                acc[r][0] += f.x*w0.x + f.y*w1.x + f.z*w2.x + f.w*w3.x;
                acc[r][1] += f.x*w0.y + f.y*w1.y + f.z*w2.y + f.w*w3.y;
                acc[r][2] += f.x*w0.z + f.y*w1.z + f.z*w2.z + f.w*w3.z;
                acc[r][3] += f.x*w0.w + f.y*w1.w + f.z*w2.w + f.w*w3.w;
            }
        }
        float4 b = *(const float4*)&bp1[jb];
#pragma unroll
        for (int r=0;r<4;++r){
            float4 o;
            o.x = fmaxf(acc[r][0]+b.x, 0.f);
            o.y = fmaxf(acc[r][1]+b.y, 0.f);
            o.z = fmaxf(acc[r][2]+b.z, 0.f);
            o.w = fmaxf(acc[r][3]+b.w, 0.f);
            *(float4*)&sh1[lr+r][jb] = o;
        }
    }
    __builtin_amdgcn_wave_barrier();
    // phase 2: semb[r][lane] = relu(sh1@Wp2 + bp2), j = lane (64 outputs)
    {
        float a2[4] = {0.f,0.f,0.f,0.f};
        for (int i=0;i<256;i+=4){
            float w0 = Wp2[(i+0)*64 + lane];
            float w1 = Wp2[(i+1)*64 + lane];
            float w2 = Wp2[(i+2)*64 + lane];
            float w3 = Wp2[(i+3)*64 + lane];
#pragma unroll
            for (int r=0;r<4;++r){
                float4 f = *(const float4*)&sh1[lr+r][i];
                a2[r] += f.x*w0 + f.y*w1 + f.z*w2 + f.w*w3;
            }
        }
        float b = bp2[lane];
#pragma unroll
        for (int r=0;r<4;++r) semb[lr+r][lane] = fmaxf(a2[r]+b, 0.f);
    }
    __builtin_amdgcn_wave_barrier();
    // phase 3: hh[r][j] = relu(semb@W1 + b1), j = lane*2, lane*2+1
    {
        int j2 = lane*2;
        float a3[4][2];
#pragma unroll
        for (int r=0;r<4;++r){ a3[r][0]=0.f; a3[r][1]=0.f; }
        for (int i=0;i<80;i+=4){
            float2 w0 = *(const float2*)&W1[(i+0)*128 + j2];
            float2 w1 = *(const float2*)&W1[(i+1)*128 + j2];
            float2 w2 = *(const float2*)&W1[(i+2)*128 + j2];
            float2 w3 = *(const float2*)&W1[(i+3)*128 + j2];
#pragma unroll
            for (int r=0;r<4;++r){
                float4 f = *(const float4*)&semb[lr+r][i];
                a3[r][0] += f.x*w0.x + f.y*w1.x + f.z*w2.x + f.w*w3.x;
                a3[r][1] += f.x*w0.y + f.y*w1.y + f.z*w2.y + f.w*w3.y;
            }
        }
        float2 bb = *(const float2*)&b1[j2];
#pragma unroll
        for (int r=0;r<4;++r){
            float2 o;
            o.x = fmaxf(a3[r][0]+bb.x, 0.f);
            o.y = fmaxf(a3[r][1]+bb.y, 0.f);
            *(float2*)&hh[(size_t)(r0+r)*128 + j2] = o;
        }
    }
}

// ---------------- edge pass: bucket-CSR with PACKED (src, weight) + last-write-wins tag
__global__ __launch_bounds__(256) void k_histtag(
    const int* __restrict__ ei, const float* __restrict__ ew,
    int* __restrict__ cnt, int2* __restrict__ bucket2, int* __restrict__ tag)
{
    int g = blockIdx.x*256 + threadIdx.x;       // < T*E
    int t = g>>14, e = g&(Ee-1);
    int a = ei[t*2*Ee + e];                     // dst
    int b = ei[t*2*Ee + Ee + e];                // src
    int cell = t*Nn + a;
    int pos = atomicAdd(&cnt[cell], 1);
    if (pos < CAP) bucket2[(size_t)cell*CAP + pos] = make_int2(b, __float_as_int(ew[g]));
    atomicMax(&tag[t*NNc + a*Nn + b], g+1);
}

// ---------------- fused: x = hh[dst] + sum w*hh[src]; h2 = relu(x @ W2 + b2)
__global__ __launch_bounds__(256) void k_sw(
    const float* __restrict__ hh, const int* __restrict__ cnt,
    const int2* __restrict__ bucket2,
    const float* __restrict__ W2, const float* __restrict__ b2,
    float* __restrict__ h2)
{
    __shared__ float sx[2][128];
    int dloc = threadIdx.x >> 7;     // 0/1
    int ch = threadIdx.x & 127;
    int bidd = blockIdx.x*2 + dloc;  // dst cell index < T*Nn
    int t = bidd >> 9;
    int n = cnt[bidd]; n = n < CAP ? n : CAP;
    const int2* __restrict__ bk = &bucket2[(size_t)bidd*CAP];
    const float* __restrict__ hht = &hh[(size_t)t*Nn*128];
    float acc = hh[(size_t)bidd*128 + ch];
    int i = 0;
    for (; i+1 < n; i += 2){
        int2 p0 = bk[i], p1 = bk[i+1];
        acc += __int_as_float(p0.y)*hht[(size_t)p0.x*128 + ch]
             + __int_as_float(p1.y)*hht[(size_t)p1.x*128 + ch];
    }
    if (i < n){
        int2 p = bk[i];
        acc += __int_as_float(p.y)*hht[(size_t)p.x*128 + ch];
    }
    sx[dloc][ch] = acc;
    __syncthreads();
    float s = 0.f;
    for (int i2=0; i2<128; i2+=4){
        float4 x = *(const float4*)&sx[dloc][i2];
        s += x.x*W2[(i2+0)*128+ch] + x.y*W2[(i2+1)*128+ch]
           + x.z*W2[(i2+2)*128+ch] + x.w*W2[(i2+3)*128+ch];
    }
    h2[(size_t)bidd*128 + ch] = fmaxf(s + b2[ch], 0.f);
}

// ---------------- edge scores via split-bf16 MFMA, fragment-pipelined
__global__ __launch_bounds__(512) void k_edge9(
    const int* __restrict__ ei, const float* __restrict__ h2,
    const uint4* __restrict__ w3h, const uint4* __restrict__ w3l,
    const float* __restrict__ b3, const float* __restrict__ w4,
    const float* __restrict__ b4, float* __restrict__ sc)
{
    __shared__ uint4 sBh[2048];   // 32 KB
    __shared__ uint4 sBl[2048];   // 32 KB
    int tid = threadIdx.x;
    int bid = blockIdx.x;                  // < 512
#pragma unroll
    for (int q=0;q<4;++q){
        sBh[q*512+tid] = w3h[q*512+tid];
        sBl[q*512+tid] = w3l[q*512+tid];
    }
    int tb  = bid >> 6;                    // timestep (64 blocks/t)
    int e0b = (bid & 63) * 256;
    int w   = tid >> 6, lane = tid & 63;
    int e0w = e0b + w*32;
    int r16 = lane & 15, g4 = lane >> 4;

    const int* __restrict__ eit = &ei[tb*2*Ee];
    int a0 = eit[e0w + r16],      s0 = eit[Ee + e0w + r16];
    int a1 = eit[e0w + 16 + r16], s1 = eit[Ee + e0w + 16 + r16];
    const float* __restrict__ pa0 = &h2[(size_t)(tb*Nn+a0)*128];
    const float* __restrict__ pb0 = &h2[(size_t)(tb*Nn+s0)*128];
    const float* __restrict__ pa1 = &h2[(size_t)(tb*Nn+a1)*128];
    const float* __restrict__ pb1 = &h2[(size_t)(tb*Nn+s1)*128];

    f32x4 acc0[8], acc1[8];
#pragma unroll
    for (int jt=0;jt<8;++jt){
        acc0[jt] = (f32x4){0.f,0.f,0.f,0.f};
        acc1[jt] = (f32x4){0.f,0.f,0.f,0.f};
    }

    float4 rA0,rA1,rB0,rB1,rC0,rC1,rD0,rD1;   // raw chunk: grp0 a/b, grp1 a/b
#define LOADK(kt) { int k0=(kt)*32+g4*8; \
    rA0=*(const float4*)&pa0[k0]; rA1=*(const float4*)&pa0[k0+4]; \
    rB0=*(const float4*)&pb0[k0]; rB1=*(const float4*)&pb0[k0+4]; \
    rC0=*(const float4*)&pa1[k0]; rC1=*(const float4*)&pa1[k0+4]; \
    rD0=*(const float4*)&pb1[k0]; rD1=*(const float4*)&pb1[k0+4]; }

    BU ah0[2], al0[2], ah1[2], al1[2];        // fragment double-buffer
#define DECK(s) { uint4 hq,lq; \
    dec2(rA0.x*rB0.x, rA0.y*rB0.y, hq.x, lq.x); \
    dec2(rA0.z*rB0.z, rA0.w*rB0.w, hq.y, lq.y); \
    dec2(rA1.x*rB1.x, rA1.y*rB1.y, hq.z, lq.z); \
    dec2(rA1.z*rB1.z, rA1.w*rB1.w, hq.w, lq.w); \
    ah0[s].q=hq; al0[s].q=lq; \
    dec2(rC0.x*rD0.x, rC0.y*rD0.y, hq.x, lq.x); \
    dec2(rC0.z*rD0.z, rC0.w*rD0.w, hq.y, lq.y); \
    dec2(rC1.x*rD1.x, rC1.y*rD1.y, hq.z, lq.z); \
    dec2(rC1.z*rD1.z, rC1.w*rD1.w, hq.w, lq.w); \
    ah1[s].q=hq; al1[s].q=lq; }

    LOADK(0)
    DECK(0)
    __syncthreads();
#pragma unroll
    for (int kt=0;kt<4;++kt){
        if (kt < 3) LOADK(kt+1)           // issue next chunk before the MFMA window
        const int s = kt & 1;
#pragma unroll
        for (int jt=0;jt<8;++jt){
            BU Bh, Bl;
            Bh.q = sBh[(kt*8+jt)*64 + lane];
            Bl.q = sBl[(kt*8+jt)*64 + lane];
            acc0[jt] = __builtin_amdgcn_mfma_f32_16x16x32_bf16(ah0[s].v, Bh.v, acc0[jt], 0,0,0);
            acc0[jt] = __builtin_amdgcn_mfma_f32_16x16x32_bf16(ah0[s].v, Bl.v, acc0[jt], 0,0,0);
            acc0[jt] = __builtin_amdgcn_mfma_f32_16x16x32_bf16(al0[s].v, Bh.v, acc0[jt], 0,0,0);
            acc1[jt] = __builtin_amdgcn_mfma_f32_16x16x32_bf16(ah1[s].v, Bh.v, acc1[jt], 0,0,0);
            acc1[jt] = __builtin_amdgcn_mfma_f32_16x16x32_bf16(ah1[s].v, Bl.v, acc1[jt], 0,0,0);
            acc1[jt] = __builtin_amdgcn_mfma_f32_16x16x32_bf16(al1[s].v, Bh.v, acc1[jt], 0,0,0);
        }
        if (kt < 3) DECK((kt+1)&1)        // convert after the window: loads have landed
    }

    float b4v = b4[0];
    float b3v[8], w4v[8];
#pragma unroll
    for (int jt=0;jt<8;++jt){ b3v[jt] = b3[jt*16 + r16]; w4v[jt] = w4[jt*16 + r16]; }
#pragma unroll
    for (int r=0;r<4;++r){
        float p0 = 0.f, p1 = 0.f;
#pragma unroll
        for (int jt=0;jt<8;++jt){
            p0 += fmaxf(acc0[jt][r] + b3v[jt], 0.f) * w4v[jt];
            p1 += fmaxf(acc1[jt][r] + b3v[jt], 0.f) * w4v[jt];
        }
        p0 += __shfl_xor(p0,1); p0 += __shfl_xor(p0,2);
        p0 += __shfl_xor(p0,4); p0 += __shfl_xor(p0,8);
        p1 += __shfl_xor(p1,1); p1 += __shfl_xor(p1,2);
        p1 += __shfl_xor(p1,4); p1 += __shfl_xor(p1,8);
        if (r16 == 0){
            sc[(size_t)tb*Ee + e0w + g4*4 + r]      = p0 + b4v;
            sc[(size_t)tb*Ee + e0w + 16 + g4*4 + r] = p1 + b4v;
        }
    }
}

// ---------------- SSM recurrence (reads tag+sc directly)
__global__ __launch_bounds__(256) void k_ssm2(
    const int* __restrict__ ei, const int* __restrict__ tag,
    const float* __restrict__ sc,
    const float* __restrict__ W_in, const float* __restrict__ conv_w,
    const float* __restrict__ conv_b, const float* __restrict__ dt_bias,
    const float* __restrict__ A_log, const float* __restrict__ D_skip,
    const float* __restrict__ W_out, float* __restrict__ out)
{
    __shared__ float scw[132], scb[33], swin[35];
    int tid = threadIdx.x;
    if (tid < 132) scw[tid] = conv_w[tid];
    if (tid < 33)  scb[tid] = conv_b[tid];
    if (tid < 35)  swin[tid] = W_in[tid];
    __syncthreads();

    int e = blockIdx.x*256 + tid;              // < E
    int a = ei[7*2*Ee + e], b = ei[7*2*Ee + Ee + e];
    int cell = a*Nn + b;
    float x[8];
#pragma unroll
    for (int t=0;t<8;++t){
        int tg = tag[t*NNc + cell];
        x[t] = (tg > 0) ? sc[tg-1] : 0.f;
    }

    float A    = -expf(A_log[0]);
    float dtb  = dt_bias[0];
    float dsk  = D_skip[0];
    float wout = W_out[0];
    float win_z = swin[0], win_dt = swin[34];

    float ssm[16];
#pragma unroll
    for (int q=0;q<16;++q) ssm[q]=0.f;
    float h0=0.f,h1=0.f,h2v=0.f;
    float y=0.f;
    for (int t=0;t<8;++t){
        float xt = x[t];
        float act[33];
#pragma unroll
        for (int c=0;c<33;++c){
            float s = h0*scw[c*4+0] + h1*scw[c*4+1] + h2v*scw[c*4+2] + xt*scw[c*4+3];
            float pre = swin[1+c]*s + scb[c];
            act[c] = pre / (1.f + expf(-pre));
        }
        float x_ = act[0];
        float dtr = xt*win_dt + dtb;
        float dt  = (dtr > 20.f) ? dtr : log1pf(expf(dtr));
        float dA  = expf(dt*A);
        float dx  = dt*x_;
        float yv = 0.f;
#pragma unroll
        for (int q=0;q<16;++q){
            ssm[q] = ssm[q]*dA + dx*act[1+q];
            yv += ssm[q]*act[17+q];
        }
        yv += dsk*x_;
        float z = xt*win_z;
        yv *= z / (1.f + expf(-z));
        y = yv;
        h0=h1; h1=h2v; h2v=xt;
    }
    out[cell] = y*wout;
}

extern "C" void kernel_launch(void* const* d_in, const int* in_sizes, int n_in,
                              void* d_out, int out_size, void* d_ws, size_t ws_size,
                              hipStream_t stream)
{
    const int*   ei    = (const int*)d_in[0];
    const float* ew    = (const float*)d_in[1];
    const float* feats = (const float*)d_in[2];
    const float* noise = (const float*)d_in[3];
    const float* Wp1=(const float*)d_in[4];  const float* bp1=(const float*)d_in[5];
    const float* Wp2=(const float*)d_in[6];  const float* bp2=(const float*)d_in[7];
    const float* W1 =(const float*)d_in[8];  const float* b1 =(const float*)d_in[9];
    const float* W2 =(const float*)d_in[10]; const float* b2 =(const float*)d_in[11];
    const float* W3 =(const float*)d_in[12]; const float* b3 =(const float*)d_in[13];
    const float* w4 =(const float*)d_in[14]; const float* b4 =(const float*)d_in[15];
    const float* W_in  =(const float*)d_in[16]; const float* conv_w=(const float*)d_in[17];
    const float* conv_b=(const float*)d_in[18]; const float* dt_bias=(const float*)d_in[19];
    const float* A_log =(const float*)d_in[20]; const float* D_skip=(const float*)d_in[21];
    const float* W_out =(const float*)d_in[22];

    float* out = (float*)d_out;
    float* ws  = (float*)d_ws;
    float* hh    = ws;                      // T*N*128  = 524288
    float* h2    = hh    + 524288;          // 524288
    float* sc    = h2    + 524288;          // T*E      = 131072
    int*   cnt   = (int*)(sc + 131072);     // T*N      = 4096
    int*   tag   = cnt + TNr;               // T*N*N    = 2097152
    int2*  bucket2 = (int2*)(tag + 2097152);           // T*N*CAP int2 = 4MB
    unsigned short* w3h = (unsigned short*)(bucket2 + (size_t)TNr*CAP);  // 16384
    unsigned short* w3l = w3h + 16384;      // 16384

    k_pf      <<<320, 256, 0, stream>>>(ei, W3, w3h, w3l, cnt, tag, (float4*)out,
                                        feats, noise, Wp1, bp1, Wp2, bp2, W1, b1, hh);
    k_histtag <<<TE/256, 256, 0, stream>>>(ei, ew, cnt, bucket2, tag);
    k_sw      <<<TNr/2, 256, 0, stream>>>(hh, cnt, bucket2, W2, b2, h2);
    k_edge9   <<<512, 512, 0, stream>>>(ei, h2, (const uint4*)w3h, (const uint4*)w3l,
                                        b3, w4, b4, sc);
    k_ssm2    <<<Ee/256, 256, 0, stream>>>(ei, tag, sc, W_in, conv_w, conv_b,
                                           dt_bias, A_log, D_skip, W_out, out);
}

// Round 16
// 105.435 us; speedup vs baseline: 1.0563x; 1.0563x over previous
//
#include <hip/hip_runtime.h>
#include <math.h>

#define Nn 512
#define Tt 8
#define Ee 16384
#define NNc (Nn*Nn)          // 262144
#define TNr (Tt*Nn)          // 4096
#define TE  (Tt*Ee)          // 131072
#define CAP 128              // bucket capacity per (t,dst); Poisson(32) => overflow ~1e-35

typedef __bf16 bf16x8 __attribute__((ext_vector_type(8)));
typedef float  f32x4  __attribute__((ext_vector_type(4)));
union BU { uint4 q; bf16x8 v; };

// RNE fp32 -> bf16 hi/lo split, packing two elements into one u32 each.
__device__ __forceinline__ void dec2(float x0, float x1, unsigned &hi, unsigned &lo){
    unsigned u0 = __float_as_uint(x0), u1 = __float_as_uint(x1);
    unsigned t0 = u0 + 0x7FFFu + ((u0>>16)&1u);
    unsigned t1 = u1 + 0x7FFFu + ((u1>>16)&1u);
    hi = (t0>>16) | (t1 & 0xFFFF0000u);
    float h0 = __uint_as_float(t0 & 0xFFFF0000u);
    float h1 = __uint_as_float(t1 & 0xFFFF0000u);
    float l0 = x0 - h0, l1 = x1 - h1;
    unsigned v0 = __float_as_uint(l0), v1 = __float_as_uint(l1);
    unsigned s0 = v0 + 0x7FFFu + ((v0>>16)&1u);
    unsigned s1 = v1 + 0x7FFFu + ((v1>>16)&1u);
    lo = (s0>>16) | (s1 & 0xFFFF0000u);
}

// ---------------- merged prep (blocks 0..63) + fp1 (blocks 64..575, 8 rows each)
// fp1: feats read as wave-uniform global loads (L1), weights coalesced per-column
// (once per block), LDS only for h1/emb handoff (uniform b128 broadcasts).
__global__ __launch_bounds__(256) void k_pf(
    const int* __restrict__ ei, const float* __restrict__ W3,
    unsigned short* __restrict__ w3h, unsigned short* __restrict__ w3l,
    int* __restrict__ cnt, int* __restrict__ tag, float4* __restrict__ out4,
    const float* __restrict__ feats, const float* __restrict__ noise,
    const float* __restrict__ Wp1, const float* __restrict__ bp1,
    const float* __restrict__ Wp2, const float* __restrict__ bp2,
    const float* __restrict__ W1, const float* __restrict__ b1,
    float* __restrict__ hh)
{
    __shared__ float sh1[8][256];    // 8 KB
    __shared__ float semb[8][80];    // 2.5 KB
    int tid = threadIdx.x;
    if (blockIdx.x < 64){
        // ---- prep: targeted zero + W3 bf16 hi/lo split in MFMA-fragment order
        int e = blockIdx.x*256 + tid;   // < 16384
        int a = ei[7*2*Ee + e], b = ei[7*2*Ee + Ee + e];
        int cell = a*Nn + b;
#pragma unroll
        for (int t=0;t<8;++t) tag[t*NNc + cell] = 0;
        if (e < TNr) cnt[e] = 0;
        float4 z = {0.f,0.f,0.f,0.f};
#pragma unroll
        for (int q=0;q<4;++q) out4[q*16384 + e] = z;
        int i    = e & 7;
        int lane = (e>>3) & 63;
        int jt   = (e>>9) & 7;
        int kt   = e>>12;
        int k = kt*32 + (lane>>4)*8 + i;
        int j = jt*16 + (lane&15);
        float x = W3[k*128 + j];
        unsigned u = __float_as_uint(x);
        unsigned t = u + 0x7FFFu + ((u>>16)&1u);
        w3h[e] = (unsigned short)(t>>16);
        float hf = __uint_as_float(t & 0xFFFF0000u);
        float lf = x - hf;
        unsigned v = __float_as_uint(lf);
        unsigned s = v + 0x7FFFu + ((v>>16)&1u);
        w3l[e] = (unsigned short)(s>>16);
        return;
    }
    // ---- fp1: 8 rows r0..r0+7 per block
    int r0 = (blockIdx.x - 64) * 8;
    // noise -> semb[:,64:80] (untouched by phase 2 writes)
    if (tid < 128){
        int r = tid>>4, k = tid&15;
        semb[r][64+k] = noise[(size_t)(r0+r)*16 + k];
    }
    // phase 1: sh1[r][tid] = relu(feats[r]@Wp1[:,tid] + bp1[tid]); feats via uniform L1 reads
    {
        const float* __restrict__ fr = &feats[(size_t)r0*128];
        float acc[8];
#pragma unroll
        for (int r=0;r<8;++r) acc[r]=0.f;
#pragma unroll 2
        for (int i=0;i<128;i+=4){
            float w0=Wp1[(i+0)*256+tid], w1=Wp1[(i+1)*256+tid];
            float w2=Wp1[(i+2)*256+tid], w3=Wp1[(i+3)*256+tid];
#pragma unroll
            for (int r=0;r<8;++r){
                float4 f = *(const float4*)&fr[r*128 + i];
                acc[r] += f.x*w0 + f.y*w1 + f.z*w2 + f.w*w3;
            }
        }
        float b = bp1[tid];
#pragma unroll
        for (int r=0;r<8;++r) sh1[r][tid] = fmaxf(acc[r]+b, 0.f);
    }
    __syncthreads();
    // phase 2: semb[r][jo] = relu(sh1[r]@Wp2[:,jo] + bp2[jo]); thread = (jo, rq) rows rq, rq+4
    {
        int jo = tid & 63, rq = tid >> 6;
        float a0=0.f, a1=0.f;
#pragma unroll 2
        for (int i=0;i<256;i+=4){
            float w0=Wp2[(i+0)*64+jo], w1=Wp2[(i+1)*64+jo];
            float w2=Wp2[(i+2)*64+jo], w3=Wp2[(i+3)*64+jo];
            float4 f0 = *(const float4*)&sh1[rq][i];
            float4 f1 = *(const float4*)&sh1[rq+4][i];
            a0 += f0.x*w0 + f0.y*w1 + f0.z*w2 + f0.w*w3;
            a1 += f1.x*w0 + f1.y*w1 + f1.z*w2 + f1.w*w3;
        }
        float b = bp2[jo];
        semb[rq][jo]   = fmaxf(a0+b, 0.f);
        semb[rq+4][jo] = fmaxf(a1+b, 0.f);
    }
    __syncthreads();
    // phase 3: hh[r][j] = relu(semb[r]@W1[:,j] + b1[j]); thread = (j, rh) rows rh,rh+2,rh+4,rh+6
    {
        int j = tid & 127, rh = tid >> 7;
        float a[4];
#pragma unroll
        for (int q=0;q<4;++q) a[q]=0.f;
#pragma unroll 2
        for (int i=0;i<80;i+=4){
            float w0=W1[(i+0)*128+j], w1=W1[(i+1)*128+j];
            float w2=W1[(i+2)*128+j], w3=W1[(i+3)*128+j];
#pragma unroll
            for (int q=0;q<4;++q){
                float4 f = *(const float4*)&semb[rh+2*q][i];
                a[q] += f.x*w0 + f.y*w1 + f.z*w2 + f.w*w3;
            }
        }
        float b = b1[j];
#pragma unroll
        for (int q=0;q<4;++q)
            hh[(size_t)(r0+rh+2*q)*128 + j] = fmaxf(a[q]+b, 0.f);
    }
}

// ---------------- edge pass: bucket-CSR with PACKED (src, weight) + last-write-wins tag
__global__ __launch_bounds__(256) void k_histtag(
    const int* __restrict__ ei, const float* __restrict__ ew,
    int* __restrict__ cnt, int2* __restrict__ bucket2, int* __restrict__ tag)
{
    int g = blockIdx.x*256 + threadIdx.x;       // < T*E
    int t = g>>14, e = g&(Ee-1);
    int a = ei[t*2*Ee + e];                     // dst
    int b = ei[t*2*Ee + Ee + e];                // src
    int cell = t*Nn + a;
    int pos = atomicAdd(&cnt[cell], 1);
    if (pos < CAP) bucket2[(size_t)cell*CAP + pos] = make_int2(b, __float_as_int(ew[g]));
    atomicMax(&tag[t*NNc + a*Nn + b], g+1);
}

// ---------------- fused: x = hh[dst] + sum w*hh[src]; h2 = relu(x @ W2 + b2)
__global__ __launch_bounds__(256) void k_sw(
    const float* __restrict__ hh, const int* __restrict__ cnt,
    const int2* __restrict__ bucket2,
    const float* __restrict__ W2, const float* __restrict__ b2,
    float* __restrict__ h2)
{
    __shared__ float sx[2][128];
    int dloc = threadIdx.x >> 7;     // 0/1
    int ch = threadIdx.x & 127;
    int bidd = blockIdx.x*2 + dloc;  // dst cell index < T*Nn
    int t = bidd >> 9;
    int n = cnt[bidd]; n = n < CAP ? n : CAP;
    const int2* __restrict__ bk = &bucket2[(size_t)bidd*CAP];
    const float* __restrict__ hht = &hh[(size_t)t*Nn*128];
    float acc = hh[(size_t)bidd*128 + ch];
    int i = 0;
    for (; i+1 < n; i += 2){
        int2 p0 = bk[i], p1 = bk[i+1];
        acc += __int_as_float(p0.y)*hht[(size_t)p0.x*128 + ch]
             + __int_as_float(p1.y)*hht[(size_t)p1.x*128 + ch];
    }
    if (i < n){
        int2 p = bk[i];
        acc += __int_as_float(p.y)*hht[(size_t)p.x*128 + ch];
    }
    sx[dloc][ch] = acc;
    __syncthreads();
    float s = 0.f;
    for (int i2=0; i2<128; i2+=4){
        float4 x = *(const float4*)&sx[dloc][i2];
        s += x.x*W2[(i2+0)*128+ch] + x.y*W2[(i2+1)*128+ch]
           + x.z*W2[(i2+2)*128+ch] + x.w*W2[(i2+3)*128+ch];
    }
    h2[(size_t)bidd*128 + ch] = fmaxf(s + b2[ch], 0.f);
}

// ---------------- edge scores via split-bf16 MFMA, fragment-pipelined
__global__ __launch_bounds__(512) void k_edge9(
    const int* __restrict__ ei, const float* __restrict__ h2,
    const uint4* __restrict__ w3h, const uint4* __restrict__ w3l,
    const float* __restrict__ b3, const float* __restrict__ w4,
    const float* __restrict__ b4, float* __restrict__ sc)
{
    __shared__ uint4 sBh[2048];   // 32 KB
    __shared__ uint4 sBl[2048];   // 32 KB
    int tid = threadIdx.x;
    int bid = blockIdx.x;                  // < 512
#pragma unroll
    for (int q=0;q<4;++q){
        sBh[q*512+tid] = w3h[q*512+tid];
        sBl[q*512+tid] = w3l[q*512+tid];
    }
    int tb  = bid >> 6;                    // timestep (64 blocks/t)
    int e0b = (bid & 63) * 256;
    int w   = tid >> 6, lane = tid & 63;
    int e0w = e0b + w*32;
    int r16 = lane & 15, g4 = lane >> 4;

    const int* __restrict__ eit = &ei[tb*2*Ee];
    int a0 = eit[e0w + r16],      s0 = eit[Ee + e0w + r16];
    int a1 = eit[e0w + 16 + r16], s1 = eit[Ee + e0w + 16 + r16];
    const float* __restrict__ pa0 = &h2[(size_t)(tb*Nn+a0)*128];
    const float* __restrict__ pb0 = &h2[(size_t)(tb*Nn+s0)*128];
    const float* __restrict__ pa1 = &h2[(size_t)(tb*Nn+a1)*128];
    const float* __restrict__ pb1 = &h2[(size_t)(tb*Nn+s1)*128];

    f32x4 acc0[8], acc1[8];
#pragma unroll
    for (int jt=0;jt<8;++jt){
        acc0[jt] = (f32x4){0.f,0.f,0.f,0.f};
        acc1[jt] = (f32x4){0.f,0.f,0.f,0.f};
    }

    float4 rA0,rA1,rB0,rB1,rC0,rC1,rD0,rD1;   // raw chunk: grp0 a/b, grp1 a/b
#define LOADK(kt) { int k0=(kt)*32+g4*8; \
    rA0=*(const float4*)&pa0[k0]; rA1=*(const float4*)&pa0[k0+4]; \
    rB0=*(const float4*)&pb0[k0]; rB1=*(const float4*)&pb0[k0+4]; \
    rC0=*(const float4*)&pa1[k0]; rC1=*(const float4*)&pa1[k0+4]; \
    rD0=*(const float4*)&pb1[k0]; rD1=*(const float4*)&pb1[k0+4]; }

    BU ah0[2], al0[2], ah1[2], al1[2];        // fragment double-buffer
#define DECK(s) { uint4 hq,lq; \
    dec2(rA0.x*rB0.x, rA0.y*rB0.y, hq.x, lq.x); \
    dec2(rA0.z*rB0.z, rA0.w*rB0.w, hq.y, lq.y); \
    dec2(rA1.x*rB1.x, rA1.y*rB1.y, hq.z, lq.z); \
    dec2(rA1.z*rB1.z, rA1.w*rB1.w, hq.w, lq.w); \
    ah0[s].q=hq; al0[s].q=lq; \
    dec2(rC0.x*rD0.x, rC0.y*rD0.y, hq.x, lq.x); \
    dec2(rC0.z*rD0.z, rC0.w*rD0.w, hq.y, lq.y); \
    dec2(rC1.x*rD1.x, rC1.y*rD1.y, hq.z, lq.z); \
    dec2(rC1.z*rD1.z, rC1.w*rD1.w, hq.w, lq.w); \
    ah1[s].q=hq; al1[s].q=lq; }

    LOADK(0)
    DECK(0)
    __syncthreads();
#pragma unroll
    for (int kt=0;kt<4;++kt){
        if (kt < 3) LOADK(kt+1)           // issue next chunk before the MFMA window
        const int s = kt & 1;
#pragma unroll
        for (int jt=0;jt<8;++jt){
            BU Bh, Bl;
            Bh.q = sBh[(kt*8+jt)*64 + lane];
            Bl.q = sBl[(kt*8+jt)*64 + lane];
            acc0[jt] = __builtin_amdgcn_mfma_f32_16x16x32_bf16(ah0[s].v, Bh.v, acc0[jt], 0,0,0);
            acc0[jt] = __builtin_amdgcn_mfma_f32_16x16x32_bf16(ah0[s].v, Bl.v, acc0[jt], 0,0,0);
            acc0[jt] = __builtin_amdgcn_mfma_f32_16x16x32_bf16(al0[s].v, Bh.v, acc0[jt], 0,0,0);
            acc1[jt] = __builtin_amdgcn_mfma_f32_16x16x32_bf16(ah1[s].v, Bh.v, acc1[jt], 0,0,0);
            acc1[jt] = __builtin_amdgcn_mfma_f32_16x16x32_bf16(ah1[s].v, Bl.v, acc1[jt], 0,0,0);
            acc1[jt] = __builtin_amdgcn_mfma_f32_16x16x32_bf16(al1[s].v, Bh.v, acc1[jt], 0,0,0);
        }
        if (kt < 3) DECK((kt+1)&1)        // convert after the window: loads have landed
    }

    float b4v = b4[0];
    float b3v[8], w4v[8];
#pragma unroll
    for (int jt=0;jt<8;++jt){ b3v[jt] = b3[jt*16 + r16]; w4v[jt] = w4[jt*16 + r16]; }
#pragma unroll
    for (int r=0;r<4;++r){
        float p0 = 0.f, p1 = 0.f;
#pragma unroll
        for (int jt=0;jt<8;++jt){
            p0 += fmaxf(acc0[jt][r] + b3v[jt], 0.f) * w4v[jt];
            p1 += fmaxf(acc1[jt][r] + b3v[jt], 0.f) * w4v[jt];
        }
        p0 += __shfl_xor(p0,1); p0 += __shfl_xor(p0,2);
        p0 += __shfl_xor(p0,4); p0 += __shfl_xor(p0,8);
        p1 += __shfl_xor(p1,1); p1 += __shfl_xor(p1,2);
        p1 += __shfl_xor(p1,4); p1 += __shfl_xor(p1,8);
        if (r16 == 0){
            sc[(size_t)tb*Ee + e0w + g4*4 + r]      = p0 + b4v;
            sc[(size_t)tb*Ee + e0w + 16 + g4*4 + r] = p1 + b4v;
        }
    }
}

// ---------------- SSM recurrence (reads tag+sc directly)
__global__ __launch_bounds__(256) void k_ssm2(
    const int* __restrict__ ei, const int* __restrict__ tag,
    const float* __restrict__ sc,
    const float* __restrict__ W_in, const float* __restrict__ conv_w,
    const float* __restrict__ conv_b, const float* __restrict__ dt_bias,
    const float* __restrict__ A_log, const float* __restrict__ D_skip,
    const float* __restrict__ W_out, float* __restrict__ out)
{
    __shared__ float scw[132], scb[33], swin[35];
    int tid = threadIdx.x;
    if (tid < 132) scw[tid] = conv_w[tid];
    if (tid < 33)  scb[tid] = conv_b[tid];
    if (tid < 35)  swin[tid] = W_in[tid];
    __syncthreads();

    int e = blockIdx.x*256 + tid;              // < E
    int a = ei[7*2*Ee + e], b = ei[7*2*Ee + Ee + e];
    int cell = a*Nn + b;
    float x[8];
#pragma unroll
    for (int t=0;t<8;++t){
        int tg = tag[t*NNc + cell];
        x[t] = (tg > 0) ? sc[tg-1] : 0.f;
    }

    float A    = -expf(A_log[0]);
    float dtb  = dt_bias[0];
    float dsk  = D_skip[0];
    float wout = W_out[0];
    float win_z = swin[0], win_dt = swin[34];

    float ssm[16];
#pragma unroll
    for (int q=0;q<16;++q) ssm[q]=0.f;
    float h0=0.f,h1=0.f,h2v=0.f;
    float y=0.f;
    for (int t=0;t<8;++t){
        float xt = x[t];
        float act[33];
#pragma unroll
        for (int c=0;c<33;++c){
            float s = h0*scw[c*4+0] + h1*scw[c*4+1] + h2v*scw[c*4+2] + xt*scw[c*4+3];
            float pre = swin[1+c]*s + scb[c];
            act[c] = pre / (1.f + expf(-pre));
        }
        float x_ = act[0];
        float dtr = xt*win_dt + dtb;
        float dt  = (dtr > 20.f) ? dtr : log1pf(expf(dtr));
        float dA  = expf(dt*A);
        float dx  = dt*x_;
        float yv = 0.f;
#pragma unroll
        for (int q=0;q<16;++q){
            ssm[q] = ssm[q]*dA + dx*act[1+q];
            yv += ssm[q]*act[17+q];
        }
        yv += dsk*x_;
        float z = xt*win_z;
        yv *= z / (1.f + expf(-z));
        y = yv;
        h0=h1; h1=h2v; h2v=xt;
    }
    out[cell] = y*wout;
}

extern "C" void kernel_launch(void* const* d_in, const int* in_sizes, int n_in,
                              void* d_out, int out_size, void* d_ws, size_t ws_size,
                              hipStream_t stream)
{
    const int*   ei    = (const int*)d_in[0];
    const float* ew    = (const float*)d_in[1];
    const float* feats = (const float*)d_in[2];
    const float* noise = (const float*)d_in[3];
    const float* Wp1=(const float*)d_in[4];  const float* bp1=(const float*)d_in[5];
    const float* Wp2=(const float*)d_in[6];  const float* bp2=(const float*)d_in[7];
    const float* W1 =(const float*)d_in[8];  const float* b1 =(const float*)d_in[9];
    const float* W2 =(const float*)d_in[10]; const float* b2 =(const float*)d_in[11];
    const float* W3 =(const float*)d_in[12]; const float* b3 =(const float*)d_in[13];
    const float* w4 =(const float*)d_in[14]; const float* b4 =(const float*)d_in[15];
    const float* W_in  =(const float*)d_in[16]; const float* conv_w=(const float*)d_in[17];
    const float* conv_b=(const float*)d_in[18]; const float* dt_bias=(const float*)d_in[19];
    const float* A_log =(const float*)d_in[20]; const float* D_skip=(const float*)d_in[21];
    const float* W_out =(const float*)d_in[22];

    float* out = (float*)d_out;
    float* ws  = (float*)d_ws;
    float* hh    = ws;                      // T*N*128  = 524288
    float* h2    = hh    + 524288;          // 524288
    float* sc    = h2    + 524288;          // T*E      = 131072
    int*   cnt   = (int*)(sc + 131072);     // T*N      = 4096
    int*   tag   = cnt + TNr;               // T*N*N    = 2097152
    int2*  bucket2 = (int2*)(tag + 2097152);           // T*N*CAP int2 = 4MB
    unsigned short* w3h = (unsigned short*)(bucket2 + (size_t)TNr*CAP);  // 16384
    unsigned short* w3l = w3h + 16384;      // 16384

    k_pf      <<<576, 256, 0, stream>>>(ei, W3, w3h, w3l, cnt, tag, (float4*)out,
                                        feats, noise, Wp1, bp1, Wp2, bp2, W1, b1, hh);
    k_histtag <<<TE/256, 256, 0, stream>>>(ei, ew, cnt, bucket2, tag);
    k_sw      <<<TNr/2, 256, 0, stream>>>(hh, cnt, bucket2, W2, b2, h2);
    k_edge9   <<<512, 512, 0, stream>>>(ei, h2, (const uint4*)w3h, (const uint4*)w3l,
                                        b3, w4, b4, sc);
    k_ssm2    <<<Ee/256, 256, 0, stream>>>(ei, tag, sc, W_in, conv_w, conv_b,
                                           dt_bias, A_log, D_skip, W_out, out);
}